// Round 6
// baseline (541.824 us; speedup 1.0000x reference)
//
#include <hip/hip_runtime.h>
#include <math.h>

typedef short s16x8 __attribute__((ext_vector_type(8)));
typedef __bf16 b16x8 __attribute__((ext_vector_type(8)));
typedef float f32x4 __attribute__((ext_vector_type(4)));
typedef unsigned int u32x4 __attribute__((ext_vector_type(4)));

__device__ inline short f2bf(float f) {
    unsigned u = __float_as_uint(f);
    unsigned r = u + 0x7FFFu + ((u >> 16) & 1u);   // RNE
    return (short)(r >> 16);
}
__device__ inline float bf2f(unsigned short u) {
    return __uint_as_float(((unsigned)u) << 16);
}

// ---------------- CSR build ----------------

__global__ void init_cnt_kernel(int* cnt, int n) {
    int i = blockIdx.x * blockDim.x + threadIdx.x;
    if (i < n) cnt[i] = 0;
}

__global__ void count_kernel(const int* __restrict__ dst, int* __restrict__ cnt, int E) {
    int e = blockIdx.x * blockDim.x + threadIdx.x;
    if (e < E) atomicAdd(&cnt[dst[e]], 1);
}

__global__ __launch_bounds__(1024) void blockscan_kernel(const int* __restrict__ cnt,
                                                         int* __restrict__ rp,
                                                         int* __restrict__ bsum, int n) {
    __shared__ int sdata[1024];
    int tid = threadIdx.x;
    int i = blockIdx.x * 1024 + tid;
    int v = (i < n) ? cnt[i] : 0;
    sdata[tid] = v;
    __syncthreads();
    for (int off = 1; off < 1024; off <<= 1) {
        int t = 0;
        if (tid >= off) t = sdata[tid - off];
        __syncthreads();
        sdata[tid] += t;
        __syncthreads();
    }
    if (i < n) rp[i] = sdata[tid] - v;       // local exclusive
    if (tid == 1023) bsum[blockIdx.x] = sdata[1023];
}

__global__ void topscan_kernel(int* bsum, int nb) {
    int lane = threadIdx.x;                   // 64 threads
    int carry = 0;
    for (int base = 0; base < nb; base += 64) {
        int idx = base + lane;
        int orig = (idx < nb) ? bsum[idx] : 0;
        int v = orig;
        for (int off = 1; off < 64; off <<= 1) {
            int t = __shfl_up(v, off, 64);
            if (lane >= off) v += t;
        }
        if (idx < nb) bsum[idx] = carry + v - orig;   // exclusive
        carry += __shfl(v, 63, 64);
    }
}

__global__ __launch_bounds__(1024) void fixup_kernel(int* __restrict__ rp,
                                                     const int* __restrict__ bsum,
                                                     const int* __restrict__ cnt,
                                                     int* __restrict__ cursor,
                                                     float* __restrict__ dinv,
                                                     int n, int E) {
    int i = blockIdx.x * 1024 + threadIdx.x;
    if (i < n) {
        int r = rp[i] + bsum[blockIdx.x];
        rp[i] = r;
        cursor[i] = r;
        dinv[i] = rsqrtf((float)cnt[i] + 1.0f);
    }
    if (i == 0) rp[n] = E;
}

__global__ void fill_kernel(const int* __restrict__ src, const int* __restrict__ dst,
                            int* __restrict__ cursor, const float* __restrict__ dinv,
                            int* __restrict__ csrc, float* __restrict__ cw, int E) {
    int e = blockIdx.x * blockDim.x + threadIdx.x;
    if (e >= E) return;
    int d = dst[e];
    int s = src[e];
    int p = atomicAdd(&cursor[d], 1);
    csrc[p] = s;
    cw[p] = dinv[s] * dinv[d];
}

// ---------------- weight pre-transpose to fragment-ready bf16 ----------------
// Wt chunk layout: [c = k0/32][b = n0/128][nt 0..7][lane 0..63][j 0..7]
//   value = W[c*32 + (lane>>4)*8 + j][b*128 + nt*16 + (lane&15)]

__global__ void make_wt_kernel(const float* __restrict__ W, short* __restrict__ Wt,
                               int K, int N) {
    int idx = blockIdx.x * blockDim.x + threadIdx.x;
    if (idx >= K * N) return;
    int NB = N >> 7;
    int j = idx & 7;
    int l = (idx >> 3) & 63;
    int nt = (idx >> 9) & 7;
    int rest = idx >> 12;
    int b = rest % NB;
    int c = rest / NB;
    int k = c * 32 + (l >> 4) * 8 + j;
    int n = b * 128 + nt * 16 + (l & 15);
    Wt[idx] = f2bf(W[(size_t)k * N + n]);
}

// ---------------- streaming MFMA GEMM, no LDS, no barriers ----------------
// Cb[MxN](bf16) = A[MxK] @ Wt (frag-ready bf16). One wave owns a 64x64 tile;
// block = NW waves covering 64 rows x N cols (NW*64 == N). Grid = ceil(M/64).
// A frags loaded global->reg (fp32 truncated to bf16 in-register, or bf16 direct);
// unroll-2 register double-buffer, sched_barrier pins the prefetch above the MFMAs.

template<typename AT, int NW>
__global__ __launch_bounds__(NW * 64, 3) void gemm_stream_kernel(
        const AT* __restrict__ A, const short* __restrict__ Wt,
        unsigned short* __restrict__ Cb, int M, int N, int K) {
    const int lane = threadIdx.x & 63;
    const int wave = threadIdx.x >> 6;
    const int m0 = blockIdx.x * 64;
    const int KC = K >> 5;
    const int NB = N >> 7;
    const int rl = lane & 15;
    const int kq = lane >> 4;                 // k-octet 0..3

    size_t aoff[4];
#pragma unroll
    for (int mt = 0; mt < 4; ++mt) {
        int r = m0 + mt * 16 + rl;
        if (r >= M) r = M - 1;                // clamp; stores are guarded
        aoff[mt] = (size_t)r * K + kq * 8;
    }
    const int nbw = (wave * 64) >> 7;         // B 128-col block
    const int ntw = (wave * 4) & 7;           // first 16-col tile within it
    const s16x8* wt = (const s16x8*)Wt;

    f32x4 acc[4][4];
#pragma unroll
    for (int i = 0; i < 4; ++i)
#pragma unroll
        for (int j = 0; j < 4; ++j)
            acc[i][j] = (f32x4){0.f, 0.f, 0.f, 0.f};

    float4 af[2][4][2];                       // fp32-A path: [set][mt][half]
    s16x8  ab[2][4];                          // bf16-A path: [set][mt]

    auto loadA = [&](int c, int s) {
        const int k0 = c << 5;
#pragma unroll
        for (int mt = 0; mt < 4; ++mt) {
            if constexpr (sizeof(AT) == 4) {
                const float* p = (const float*)A + aoff[mt] + k0;
                af[s][mt][0] = *(const float4*)p;
                af[s][mt][1] = *(const float4*)(p + 4);
            } else {
                ab[s][mt] = *(const s16x8*)((const unsigned short*)A + aoff[mt] + k0);
            }
        }
    };

    auto mfmaStep = [&](int c, int s) {
        b16x8 breg[4];
        size_t bbase = (size_t)(c * NB + nbw) * 512 + (size_t)ntw * 64 + lane;
#pragma unroll
        for (int j = 0; j < 4; ++j)
            breg[j] = __builtin_bit_cast(b16x8, wt[bbase + j * 64]);
        b16x8 areg[4];
#pragma unroll
        for (int mt = 0; mt < 4; ++mt) {
            if constexpr (sizeof(AT) == 4) {
                u32x4 pk;
                pk.x = (__float_as_uint(af[s][mt][0].x) >> 16) | (__float_as_uint(af[s][mt][0].y) & 0xFFFF0000u);
                pk.y = (__float_as_uint(af[s][mt][0].z) >> 16) | (__float_as_uint(af[s][mt][0].w) & 0xFFFF0000u);
                pk.z = (__float_as_uint(af[s][mt][1].x) >> 16) | (__float_as_uint(af[s][mt][1].y) & 0xFFFF0000u);
                pk.w = (__float_as_uint(af[s][mt][1].z) >> 16) | (__float_as_uint(af[s][mt][1].w) & 0xFFFF0000u);
                areg[mt] = __builtin_bit_cast(b16x8, pk);
            } else {
                areg[mt] = __builtin_bit_cast(b16x8, ab[s][mt]);
            }
        }
#pragma unroll
        for (int i = 0; i < 4; ++i)
#pragma unroll
            for (int j = 0; j < 4; ++j)
                acc[i][j] = __builtin_amdgcn_mfma_f32_16x16x32_bf16(areg[i], breg[j], acc[i][j], 0, 0, 0);
    };

    loadA(0, 0);
    for (int c = 0; c < KC; c += 2) {         // KC is even (24 or 8)
        loadA(c + 1, 1);                      // prefetch next chunk
        __builtin_amdgcn_sched_barrier(0);    // keep prefetch above the MFMAs
        mfmaStep(c, 0);
        loadA(c + 2 < KC ? c + 2 : c, 0);     // clamp: last prefetch unused
        __builtin_amdgcn_sched_barrier(0);
        mfmaStep(c + 1, 1);
    }

    const int quad = lane >> 4;
    const int nl = lane & 15;
#pragma unroll
    for (int i = 0; i < 4; ++i) {
        int rbase = m0 + i * 16 + quad * 4;
#pragma unroll
        for (int j = 0; j < 4; ++j) {
            int col = wave * 64 + j * 16 + nl;
#pragma unroll
            for (int r = 0; r < 4; ++r) {
                int row = rbase + r;
                if (row < M) Cb[(size_t)row * N + col] = (unsigned short)f2bf(acc[i][j][r]);
            }
        }
    }
}

// ---------------- aggregation, bf16 in ----------------

__global__ __launch_bounds__(256) void agg256_kernel(const unsigned short* __restrict__ h,
                                                     const int* __restrict__ rp,
                                                     const int* __restrict__ csrc,
                                                     const float* __restrict__ cw,
                                                     const float* __restrict__ dinv,
                                                     const float* __restrict__ bias,
                                                     unsigned short* __restrict__ out, int n) {
    int node = blockIdx.x * 4 + (threadIdx.x >> 6);
    int lane = threadIdx.x & 63;
    if (node >= n) return;
    const ushort4* hp = (const ushort4*)h;       // 64 per row
    float di = dinv[node];
    float ws = di * di;
    ushort4 sv = hp[(size_t)node * 64 + lane];
    float a0 = ws * bf2f(sv.x), a1 = ws * bf2f(sv.y), a2 = ws * bf2f(sv.z), a3 = ws * bf2f(sv.w);
    int e = rp[node], e1 = rp[node + 1];
    for (; e + 1 < e1; e += 2) {
        int s0 = csrc[e], s1 = csrc[e + 1];
        float w0 = cw[e], w1 = cw[e + 1];
        ushort4 v0 = hp[(size_t)s0 * 64 + lane];
        ushort4 v1 = hp[(size_t)s1 * 64 + lane];
        a0 += w0 * bf2f(v0.x) + w1 * bf2f(v1.x);
        a1 += w0 * bf2f(v0.y) + w1 * bf2f(v1.y);
        a2 += w0 * bf2f(v0.z) + w1 * bf2f(v1.z);
        a3 += w0 * bf2f(v0.w) + w1 * bf2f(v1.w);
    }
    if (e < e1) {
        int s0 = csrc[e];
        float w0 = cw[e];
        ushort4 v0 = hp[(size_t)s0 * 64 + lane];
        a0 += w0 * bf2f(v0.x); a1 += w0 * bf2f(v0.y);
        a2 += w0 * bf2f(v0.z); a3 += w0 * bf2f(v0.w);
    }
    float4 bv = *(const float4*)&bias[lane * 4];
    a0 = fmaxf(a0 + bv.x, 0.f); a1 = fmaxf(a1 + bv.y, 0.f);
    a2 = fmaxf(a2 + bv.z, 0.f); a3 = fmaxf(a3 + bv.w, 0.f);
    ushort4 ov;
    ov.x = (unsigned short)f2bf(a0); ov.y = (unsigned short)f2bf(a1);
    ov.z = (unsigned short)f2bf(a2); ov.w = (unsigned short)f2bf(a3);
    ((ushort4*)out)[(size_t)node * 64 + lane] = ov;
}

__global__ __launch_bounds__(256) void agg128_w3_kernel(const unsigned short* __restrict__ h,
                                                        const int* __restrict__ rp,
                                                        const int* __restrict__ csrc,
                                                        const float* __restrict__ cw,
                                                        const float* __restrict__ dinv,
                                                        const float* __restrict__ b2,
                                                        const float* __restrict__ W3,
                                                        float* __restrict__ z, int n) {
    int node = blockIdx.x * 4 + (threadIdx.x >> 6);
    int lane = threadIdx.x & 63;
    if (node >= n) return;
    const unsigned* hp = (const unsigned*)h;     // 64 uints per row (2 bf16 each)
    float di = dinv[node];
    float ws = di * di;
    unsigned sv = hp[(size_t)node * 64 + lane];
    float a0 = ws * __uint_as_float(sv << 16);
    float a1 = ws * __uint_as_float(sv & 0xFFFF0000u);
    int e = rp[node], e1 = rp[node + 1];
    for (; e + 1 < e1; e += 2) {
        int s0 = csrc[e], s1 = csrc[e + 1];
        float w0 = cw[e], w1 = cw[e + 1];
        unsigned v0 = hp[(size_t)s0 * 64 + lane];
        unsigned v1 = hp[(size_t)s1 * 64 + lane];
        a0 += w0 * __uint_as_float(v0 << 16) + w1 * __uint_as_float(v1 << 16);
        a1 += w0 * __uint_as_float(v0 & 0xFFFF0000u) + w1 * __uint_as_float(v1 & 0xFFFF0000u);
    }
    if (e < e1) {
        int s0 = csrc[e];
        float w0 = cw[e];
        unsigned v0 = hp[(size_t)s0 * 64 + lane];
        a0 += w0 * __uint_as_float(v0 << 16);
        a1 += w0 * __uint_as_float(v0 & 0xFFFF0000u);
    }
    float2 bv = *(const float2*)&b2[lane * 2];
    a0 = fmaxf(a0 + bv.x, 0.f);
    a1 = fmaxf(a1 + bv.y, 0.f);
    float4 wv = *(const float4*)&W3[lane * 4];
    float z0 = a0 * wv.x + a1 * wv.z;
    float z1 = a0 * wv.y + a1 * wv.w;
    for (int off = 32; off > 0; off >>= 1) {
        z0 += __shfl_down(z0, off, 64);
        z1 += __shfl_down(z1, off, 64);
    }
    if (lane == 0) {
        z[2 * (size_t)node] = z0;
        z[2 * (size_t)node + 1] = z1;
    }
}

__global__ void agg3_kernel(const float* __restrict__ z, const int* __restrict__ rp,
                            const int* __restrict__ csrc, const float* __restrict__ cw,
                            const float* __restrict__ dinv, const float* __restrict__ bias,
                            float* __restrict__ out, int n) {
    int node = blockIdx.x * blockDim.x + threadIdx.x;
    if (node >= n) return;
    float di = dinv[node];
    float a0 = di * di * z[2 * (size_t)node];
    float a1 = di * di * z[2 * (size_t)node + 1];
    int e1 = rp[node + 1];
    for (int e = rp[node]; e < e1; ++e) {
        int s = csrc[e];
        float w = cw[e];
        a0 += w * z[2 * (size_t)s];
        a1 += w * z[2 * (size_t)s + 1];
    }
    a0 += bias[0];
    a1 += bias[1];
    out[2 * (size_t)node]     = 1.f / (1.f + __expf(-a0));
    out[2 * (size_t)node + 1] = 1.f / (1.f + __expf(-a1));
}

// ---------------- launch ----------------

extern "C" void kernel_launch(void* const* d_in, const int* in_sizes, int n_in,
                              void* d_out, int out_size, void* d_ws, size_t ws_size,
                              hipStream_t stream) {
    const float* x  = (const float*)d_in[0];
    const int*   ei = (const int*)d_in[1];
    const float* W1 = (const float*)d_in[2];
    const float* b1 = (const float*)d_in[3];
    const float* W2 = (const float*)d_in[4];
    const float* b2 = (const float*)d_in[5];
    const float* W3 = (const float*)d_in[6];
    const float* b3 = (const float*)d_in[7];
    float* out = (float*)d_out;

    const int E  = in_sizes[1] / 2;
    const int C1 = in_sizes[3];              // 256
    const int C2 = in_sizes[5];              // 128
    const int K1 = in_sizes[2] / C1;         // 768
    const int N  = in_sizes[0] / K1;         // 50000

    const int* srcv = ei;
    const int* dstv = ei + E;

    char* p = (char*)d_ws;
    auto carve = [&](size_t bytes) {
        char* r = p;
        p += (bytes + 255) & ~(size_t)255;
        return r;
    };
    int*   cnt    = (int*)carve((size_t)N * 4);
    int*   rp     = (int*)carve((size_t)(N + 1) * 4);
    int*   cursor = (int*)carve((size_t)N * 4);
    float* dinv   = (float*)carve((size_t)N * 4);
    int*   bsum   = (int*)carve(1024 * 4);
    int*   csrc   = (int*)carve((size_t)E * 4);
    float* cw     = (float*)carve((size_t)E * 4);
    short* Wt1    = (short*)carve((size_t)K1 * C1 * 2);
    short* Wt2    = (short*)carve((size_t)C1 * C2 * 2);
    unsigned short* hA = (unsigned short*)carve((size_t)N * C1 * 2);
    unsigned short* hB = (unsigned short*)carve((size_t)N * C1 * 2);
    float* zbuf   = (float*)carve((size_t)N * 2 * 4);

    const int nb = (N + 1023) / 1024;

    // CSR build
    init_cnt_kernel<<<(N + 255) / 256, 256, 0, stream>>>(cnt, N);
    count_kernel<<<(E + 255) / 256, 256, 0, stream>>>(dstv, cnt, E);
    blockscan_kernel<<<nb, 1024, 0, stream>>>(cnt, rp, bsum, N);
    topscan_kernel<<<1, 64, 0, stream>>>(bsum, nb);
    fixup_kernel<<<nb, 1024, 0, stream>>>(rp, bsum, cnt, cursor, dinv, N, E);
    fill_kernel<<<(E + 255) / 256, 256, 0, stream>>>(srcv, dstv, cursor, dinv, csrc, cw, E);

    // Weight pre-transpose (fragment-ready bf16)
    make_wt_kernel<<<(K1 * C1 + 255) / 256, 256, 0, stream>>>(W1, Wt1, K1, C1);
    make_wt_kernel<<<(C1 * C2 + 255) / 256, 256, 0, stream>>>(W2, Wt2, C1, C2);

    const int gm = (N + 63) / 64;            // 782 row blocks

    // Layer 1: h1 = x @ W1 ; a1 = relu(Ahat h1 + b1)
    gemm_stream_kernel<float, 4><<<gm, 256, 0, stream>>>(x, Wt1, hA, N, C1, K1);
    agg256_kernel<<<(N + 3) / 4, 256, 0, stream>>>(hA, rp, csrc, cw, dinv, b1, hB, N);

    // Layer 2: h2 = a1 @ W2 ; fused a2 = relu(Ahat h2 + b2), z = a2 @ W3
    gemm_stream_kernel<unsigned short, 2><<<gm, 128, 0, stream>>>(hB, Wt2, hA, N, C2, C1);
    agg128_w3_kernel<<<(N + 3) / 4, 256, 0, stream>>>(hA, rp, csrc, cw, dinv, b2, W3, zbuf, N);

    // Layer 3 aggregation + sigmoid
    agg3_kernel<<<(N + 255) / 256, 256, 0, stream>>>(zbuf, rp, csrc, cw, dinv, b3, out, N);
}

// Round 7
// 508.300 us; speedup vs baseline: 1.0660x; 1.0660x over previous
//
#include <hip/hip_runtime.h>
#include <math.h>

typedef short s16x8 __attribute__((ext_vector_type(8)));
typedef __bf16 b16x8 __attribute__((ext_vector_type(8)));
typedef float f32x4 __attribute__((ext_vector_type(4)));
typedef unsigned int u32x4 __attribute__((ext_vector_type(4)));

__device__ inline short f2bf(float f) {
    unsigned u = __float_as_uint(f);
    unsigned r = u + 0x7FFFu + ((u >> 16) & 1u);   // RNE
    return (short)(r >> 16);
}
__device__ inline float bf2f(unsigned short u) {
    return __uint_as_float(((unsigned)u) << 16);
}

// ---------------- CSR build ----------------

__global__ void init_cnt_kernel(int* cnt, int n) {
    int i = blockIdx.x * blockDim.x + threadIdx.x;
    if (i < n) cnt[i] = 0;
}

__global__ void count_kernel(const int* __restrict__ dst, int* __restrict__ cnt, int E) {
    int e = blockIdx.x * blockDim.x + threadIdx.x;
    if (e < E) atomicAdd(&cnt[dst[e]], 1);
}

__global__ __launch_bounds__(1024) void blockscan_kernel(const int* __restrict__ cnt,
                                                         int* __restrict__ rp,
                                                         int* __restrict__ bsum, int n) {
    __shared__ int sdata[1024];
    int tid = threadIdx.x;
    int i = blockIdx.x * 1024 + tid;
    int v = (i < n) ? cnt[i] : 0;
    sdata[tid] = v;
    __syncthreads();
    for (int off = 1; off < 1024; off <<= 1) {
        int t = 0;
        if (tid >= off) t = sdata[tid - off];
        __syncthreads();
        sdata[tid] += t;
        __syncthreads();
    }
    if (i < n) rp[i] = sdata[tid] - v;       // local exclusive
    if (tid == 1023) bsum[blockIdx.x] = sdata[1023];
}

__global__ void topscan_kernel(int* bsum, int nb) {
    int lane = threadIdx.x;                   // 64 threads
    int carry = 0;
    for (int base = 0; base < nb; base += 64) {
        int idx = base + lane;
        int orig = (idx < nb) ? bsum[idx] : 0;
        int v = orig;
        for (int off = 1; off < 64; off <<= 1) {
            int t = __shfl_up(v, off, 64);
            if (lane >= off) v += t;
        }
        if (idx < nb) bsum[idx] = carry + v - orig;   // exclusive
        carry += __shfl(v, 63, 64);
    }
}

__global__ __launch_bounds__(1024) void fixup_kernel(int* __restrict__ rp,
                                                     const int* __restrict__ bsum,
                                                     const int* __restrict__ cnt,
                                                     int* __restrict__ cursor,
                                                     float* __restrict__ dinv,
                                                     int n, int E) {
    int i = blockIdx.x * 1024 + threadIdx.x;
    if (i < n) {
        int r = rp[i] + bsum[blockIdx.x];
        rp[i] = r;
        cursor[i] = r;
        dinv[i] = rsqrtf((float)cnt[i] + 1.0f);
    }
    if (i == 0) rp[n] = E;
}

__global__ void fill_kernel(const int* __restrict__ src, const int* __restrict__ dst,
                            int* __restrict__ cursor, const float* __restrict__ dinv,
                            int* __restrict__ csrc, float* __restrict__ cw, int E) {
    int e = blockIdx.x * blockDim.x + threadIdx.x;
    if (e >= E) return;
    int d = dst[e];
    int s = src[e];
    int p = atomicAdd(&cursor[d], 1);
    csrc[p] = s;
    cw[p] = dinv[s] * dinv[d];
}

// ---------------- weight pre-transpose to fragment-ready bf16 ----------------
// Wt chunk layout: [c = k0/32][b = n0/128][nt 0..7][lane 0..63][j 0..7]
//   value = W[c*32 + (lane>>4)*8 + j][b*128 + nt*16 + (lane&15)]

__global__ void make_wt_kernel(const float* __restrict__ W, short* __restrict__ Wt,
                               int K, int N) {
    int idx = blockIdx.x * blockDim.x + threadIdx.x;
    if (idx >= K * N) return;
    int NB = N >> 7;
    int j = idx & 7;
    int l = (idx >> 3) & 63;
    int nt = (idx >> 9) & 7;
    int rest = idx >> 12;
    int b = rest % NB;
    int c = rest / NB;
    int k = c * 32 + (l >> 4) * 8 + j;
    int n = b * 128 + nt * 16 + (l & 15);
    Wt[idx] = f2bf(W[(size_t)k * N + n]);
}

// ---------------- row-panel GEMM: barrier-free K-loop ----------------
// C[M x CW*64](bf16) = A[M x KC*32] @ Wt (frag-ready bf16).
// Block = RT*16 rows x CW*64 cols, 256 threads = 4 waves.
// A row-panel staged ONCE into LDS (fragment-ready, swizzled); K-loop then has
// NO barriers: ds_read A-frags + global-load B-frags (L2-resident Wt) + MFMA.
// Swizzle: frag (c,mt), slot = q*16 + ((rlow + q + 4*(c&3)) & 15) -> bank-rotated.

template<typename AT, int KC, int RT, int CW, int MINW>
__global__ __launch_bounds__(256, MINW) void gemm_panel_kernel(
        const AT* __restrict__ A, const short* __restrict__ Wt,
        unsigned short* __restrict__ Cb, int M) {
    constexpr int K = KC * 32;
    constexpr int O = KC * 4;              // 8-elem octets per row
    constexpr int F = KC * RT / 4;         // frags staged per thread
    constexpr int NCOLS = CW * 64;
    constexpr int NB = NCOLS >> 7;         // 128-col B blocks
    constexpr int MT = RT * CW / 4;        // m-tiles per wave

    __shared__ s16x8 As[KC * RT * 64];

    const int tid = threadIdx.x;
    const int m0 = blockIdx.x * (RT * 16);

    // ---- stage A row-panel (once) ----
    if constexpr (sizeof(AT) == 4) {
        float4 f0[F], f1[F];
#pragma unroll
        for (int i = 0; i < F; ++i) {
            int idx = i * 256 + tid;
            int r = idx / O;
            int o = idx - r * O;
            int row = m0 + r;
            if (row >= M) row = M - 1;
            const float* p = (const float*)A + (size_t)row * K + o * 8;
            f0[i] = *(const float4*)p;
            f1[i] = *(const float4*)(p + 4);
        }
#pragma unroll
        for (int i = 0; i < F; ++i) {
            int idx = i * 256 + tid;
            int r = idx / O;
            int o = idx - r * O;
            int c = o >> 2, q = o & 3;
            u32x4 pk;
            pk.x = (__float_as_uint(f0[i].x) >> 16) | (__float_as_uint(f0[i].y) & 0xFFFF0000u);
            pk.y = (__float_as_uint(f0[i].z) >> 16) | (__float_as_uint(f0[i].w) & 0xFFFF0000u);
            pk.z = (__float_as_uint(f1[i].x) >> 16) | (__float_as_uint(f1[i].y) & 0xFFFF0000u);
            pk.w = (__float_as_uint(f1[i].z) >> 16) | (__float_as_uint(f1[i].w) & 0xFFFF0000u);
            int slot = q * 16 + (((r & 15) + q + ((c & 3) << 2)) & 15);
            As[(c * RT + (r >> 4)) * 64 + slot] = __builtin_bit_cast(s16x8, pk);
        }
    } else {
        s16x8 v[F];
#pragma unroll
        for (int i = 0; i < F; ++i) {
            int idx = i * 256 + tid;
            int r = idx / O;
            int o = idx - r * O;
            int row = m0 + r;
            if (row >= M) row = M - 1;
            v[i] = *(const s16x8*)((const unsigned short*)A + (size_t)row * K + o * 8);
        }
#pragma unroll
        for (int i = 0; i < F; ++i) {
            int idx = i * 256 + tid;
            int r = idx / O;
            int o = idx - r * O;
            int c = o >> 2, q = o & 3;
            int slot = q * 16 + (((r & 15) + q + ((c & 3) << 2)) & 15);
            As[(c * RT + (r >> 4)) * 64 + slot] = v[i];
        }
    }
    __syncthreads();

    // ---- barrier-free K-loop ----
    const int lane = tid & 63;
    const int wave = tid >> 6;
    const int cw_i = wave % CW;
    const int rg = wave / CW;
    const int mtb = rg * MT;
    const int b128 = (cw_i * 64) >> 7;
    const int nt0 = (cw_i * 4) & 7;
    const int q = lane >> 4;
    const int rl = lane & 15;
    const s16x8* wt = (const s16x8*)Wt;

    f32x4 acc[MT][4];
#pragma unroll
    for (int i = 0; i < MT; ++i)
#pragma unroll
        for (int j = 0; j < 4; ++j)
            acc[i][j] = (f32x4){0.f, 0.f, 0.f, 0.f};

#pragma unroll 4
    for (int c = 0; c < KC; ++c) {
        int slot = q * 16 + ((rl + q + ((c & 3) << 2)) & 15);
        b16x8 areg[MT], breg[4];
#pragma unroll
        for (int i = 0; i < MT; ++i)
            areg[i] = __builtin_bit_cast(b16x8, As[(c * RT + mtb + i) * 64 + slot]);
        size_t bb = (size_t)(c * NB + b128) * 512 + nt0 * 64 + lane;
#pragma unroll
        for (int j = 0; j < 4; ++j)
            breg[j] = __builtin_bit_cast(b16x8, wt[bb + j * 64]);
#pragma unroll
        for (int i = 0; i < MT; ++i)
#pragma unroll
            for (int j = 0; j < 4; ++j)
                acc[i][j] = __builtin_amdgcn_mfma_f32_16x16x32_bf16(areg[i], breg[j], acc[i][j], 0, 0, 0);
    }

    // ---- store ----
    const int quad = lane >> 4;
    const int nl = lane & 15;
#pragma unroll
    for (int i = 0; i < MT; ++i) {
        int rbase = m0 + (mtb + i) * 16 + quad * 4;
#pragma unroll
        for (int j = 0; j < 4; ++j) {
            int col = cw_i * 64 + j * 16 + nl;
#pragma unroll
            for (int rr = 0; rr < 4; ++rr) {
                int row = rbase + rr;
                if (row < M) Cb[(size_t)row * NCOLS + col] = (unsigned short)f2bf(acc[i][j][rr]);
            }
        }
    }
}

// ---------------- aggregation, bf16 in ----------------

__global__ __launch_bounds__(256) void agg256_kernel(const unsigned short* __restrict__ h,
                                                     const int* __restrict__ rp,
                                                     const int* __restrict__ csrc,
                                                     const float* __restrict__ cw,
                                                     const float* __restrict__ dinv,
                                                     const float* __restrict__ bias,
                                                     unsigned short* __restrict__ out, int n) {
    int node = blockIdx.x * 4 + (threadIdx.x >> 6);
    int lane = threadIdx.x & 63;
    if (node >= n) return;
    const ushort4* hp = (const ushort4*)h;       // 64 per row
    float di = dinv[node];
    float ws = di * di;
    ushort4 sv = hp[(size_t)node * 64 + lane];
    float a0 = ws * bf2f(sv.x), a1 = ws * bf2f(sv.y), a2 = ws * bf2f(sv.z), a3 = ws * bf2f(sv.w);
    int e = rp[node], e1 = rp[node + 1];
    for (; e + 1 < e1; e += 2) {
        int s0 = csrc[e], s1 = csrc[e + 1];
        float w0 = cw[e], w1 = cw[e + 1];
        ushort4 v0 = hp[(size_t)s0 * 64 + lane];
        ushort4 v1 = hp[(size_t)s1 * 64 + lane];
        a0 += w0 * bf2f(v0.x) + w1 * bf2f(v1.x);
        a1 += w0 * bf2f(v0.y) + w1 * bf2f(v1.y);
        a2 += w0 * bf2f(v0.z) + w1 * bf2f(v1.z);
        a3 += w0 * bf2f(v0.w) + w1 * bf2f(v1.w);
    }
    if (e < e1) {
        int s0 = csrc[e];
        float w0 = cw[e];
        ushort4 v0 = hp[(size_t)s0 * 64 + lane];
        a0 += w0 * bf2f(v0.x); a1 += w0 * bf2f(v0.y);
        a2 += w0 * bf2f(v0.z); a3 += w0 * bf2f(v0.w);
    }
    float4 bv = *(const float4*)&bias[lane * 4];
    a0 = fmaxf(a0 + bv.x, 0.f); a1 = fmaxf(a1 + bv.y, 0.f);
    a2 = fmaxf(a2 + bv.z, 0.f); a3 = fmaxf(a3 + bv.w, 0.f);
    ushort4 ov;
    ov.x = (unsigned short)f2bf(a0); ov.y = (unsigned short)f2bf(a1);
    ov.z = (unsigned short)f2bf(a2); ov.w = (unsigned short)f2bf(a3);
    ((ushort4*)out)[(size_t)node * 64 + lane] = ov;
}

__global__ __launch_bounds__(256) void agg128_w3_kernel(const unsigned short* __restrict__ h,
                                                        const int* __restrict__ rp,
                                                        const int* __restrict__ csrc,
                                                        const float* __restrict__ cw,
                                                        const float* __restrict__ dinv,
                                                        const float* __restrict__ b2,
                                                        const float* __restrict__ W3,
                                                        float* __restrict__ z, int n) {
    int node = blockIdx.x * 4 + (threadIdx.x >> 6);
    int lane = threadIdx.x & 63;
    if (node >= n) return;
    const unsigned* hp = (const unsigned*)h;     // 64 uints per row (2 bf16 each)
    float di = dinv[node];
    float ws = di * di;
    unsigned sv = hp[(size_t)node * 64 + lane];
    float a0 = ws * __uint_as_float(sv << 16);
    float a1 = ws * __uint_as_float(sv & 0xFFFF0000u);
    int e = rp[node], e1 = rp[node + 1];
    for (; e + 1 < e1; e += 2) {
        int s0 = csrc[e], s1 = csrc[e + 1];
        float w0 = cw[e], w1 = cw[e + 1];
        unsigned v0 = hp[(size_t)s0 * 64 + lane];
        unsigned v1 = hp[(size_t)s1 * 64 + lane];
        a0 += w0 * __uint_as_float(v0 << 16) + w1 * __uint_as_float(v1 << 16);
        a1 += w0 * __uint_as_float(v0 & 0xFFFF0000u) + w1 * __uint_as_float(v1 & 0xFFFF0000u);
    }
    if (e < e1) {
        int s0 = csrc[e];
        float w0 = cw[e];
        unsigned v0 = hp[(size_t)s0 * 64 + lane];
        a0 += w0 * __uint_as_float(v0 << 16);
        a1 += w0 * __uint_as_float(v0 & 0xFFFF0000u);
    }
    float2 bv = *(const float2*)&b2[lane * 2];
    a0 = fmaxf(a0 + bv.x, 0.f);
    a1 = fmaxf(a1 + bv.y, 0.f);
    float4 wv = *(const float4*)&W3[lane * 4];
    float z0 = a0 * wv.x + a1 * wv.z;
    float z1 = a0 * wv.y + a1 * wv.w;
    for (int off = 32; off > 0; off >>= 1) {
        z0 += __shfl_down(z0, off, 64);
        z1 += __shfl_down(z1, off, 64);
    }
    if (lane == 0) {
        z[2 * (size_t)node] = z0;
        z[2 * (size_t)node + 1] = z1;
    }
}

__global__ void agg3_kernel(const float* __restrict__ z, const int* __restrict__ rp,
                            const int* __restrict__ csrc, const float* __restrict__ cw,
                            const float* __restrict__ dinv, const float* __restrict__ bias,
                            float* __restrict__ out, int n) {
    int node = blockIdx.x * blockDim.x + threadIdx.x;
    if (node >= n) return;
    float di = dinv[node];
    float a0 = di * di * z[2 * (size_t)node];
    float a1 = di * di * z[2 * (size_t)node + 1];
    int e1 = rp[node + 1];
    for (int e = rp[node]; e < e1; ++e) {
        int s = csrc[e];
        float w = cw[e];
        a0 += w * z[2 * (size_t)s];
        a1 += w * z[2 * (size_t)s + 1];
    }
    a0 += bias[0];
    a1 += bias[1];
    out[2 * (size_t)node]     = 1.f / (1.f + __expf(-a0));
    out[2 * (size_t)node + 1] = 1.f / (1.f + __expf(-a1));
}

// ---------------- launch ----------------

extern "C" void kernel_launch(void* const* d_in, const int* in_sizes, int n_in,
                              void* d_out, int out_size, void* d_ws, size_t ws_size,
                              hipStream_t stream) {
    const float* x  = (const float*)d_in[0];
    const int*   ei = (const int*)d_in[1];
    const float* W1 = (const float*)d_in[2];
    const float* b1 = (const float*)d_in[3];
    const float* W2 = (const float*)d_in[4];
    const float* b2 = (const float*)d_in[5];
    const float* W3 = (const float*)d_in[6];
    const float* b3 = (const float*)d_in[7];
    float* out = (float*)d_out;

    const int E  = in_sizes[1] / 2;
    const int C1 = in_sizes[3];              // 256
    const int C2 = in_sizes[5];              // 128
    const int K1 = in_sizes[2] / C1;         // 768
    const int N  = in_sizes[0] / K1;         // 50000

    const int* srcv = ei;
    const int* dstv = ei + E;

    char* p = (char*)d_ws;
    auto carve = [&](size_t bytes) {
        char* r = p;
        p += (bytes + 255) & ~(size_t)255;
        return r;
    };
    int*   cnt    = (int*)carve((size_t)N * 4);
    int*   rp     = (int*)carve((size_t)(N + 1) * 4);
    int*   cursor = (int*)carve((size_t)N * 4);
    float* dinv   = (float*)carve((size_t)N * 4);
    int*   bsum   = (int*)carve(1024 * 4);
    int*   csrc   = (int*)carve((size_t)E * 4);
    float* cw     = (float*)carve((size_t)E * 4);
    short* Wt1    = (short*)carve((size_t)K1 * C1 * 2);
    short* Wt2    = (short*)carve((size_t)C1 * C2 * 2);
    unsigned short* hA = (unsigned short*)carve((size_t)N * C1 * 2);
    unsigned short* hB = (unsigned short*)carve((size_t)N * C1 * 2);
    float* zbuf   = (float*)carve((size_t)N * 2 * 4);

    const int nb = (N + 1023) / 1024;

    // CSR build
    init_cnt_kernel<<<(N + 255) / 256, 256, 0, stream>>>(cnt, N);
    count_kernel<<<(E + 255) / 256, 256, 0, stream>>>(dstv, cnt, E);
    blockscan_kernel<<<nb, 1024, 0, stream>>>(cnt, rp, bsum, N);
    topscan_kernel<<<1, 64, 0, stream>>>(bsum, nb);
    fixup_kernel<<<nb, 1024, 0, stream>>>(rp, bsum, cnt, cursor, dinv, N, E);
    fill_kernel<<<(E + 255) / 256, 256, 0, stream>>>(srcv, dstv, cursor, dinv, csrc, cw, E);

    // Weight pre-transpose (fragment-ready bf16)
    make_wt_kernel<<<(K1 * C1 + 255) / 256, 256, 0, stream>>>(W1, Wt1, K1, C1);
    make_wt_kernel<<<(C1 * C2 + 255) / 256, 256, 0, stream>>>(W2, Wt2, C1, C2);

    // Layer 1: h1 = x @ W1 (32-row panels, 1563 blocks) ; a1 = relu(Ahat h1 + b1)
    gemm_panel_kernel<float, 24, 2, 4, 3><<<(N + 31) / 32, 256, 0, stream>>>(x, Wt1, hA, N);
    agg256_kernel<<<(N + 3) / 4, 256, 0, stream>>>(hA, rp, csrc, cw, dinv, b1, hB, N);

    // Layer 2: h2 = a1 @ W2 (64-row panels, 782 blocks) ; fused a2+W3
    gemm_panel_kernel<unsigned short, 8, 4, 2, 4><<<(N + 63) / 64, 256, 0, stream>>>(hB, Wt2, hA, N);
    agg128_w3_kernel<<<(N + 3) / 4, 256, 0, stream>>>(hA, rp, csrc, cw, dinv, b2, W3, zbuf, N);

    // Layer 3 aggregation + sigmoid
    agg3_kernel<<<(N + 255) / 256, 256, 0, stream>>>(zbuf, rp, csrc, cw, dinv, b3, out, N);
}